// Round 6
// baseline (431.169 us; speedup 1.0000x reference)
//
#include <hip/hip_runtime.h>

// MemoryReader: B=4, CK=64, T=8, H=W=32 -> N=8192 mem tokens, M=1024 queries, CV=512.
// Inputs fp32, OUTPUT fp32 (rounds 2-4 wrote bf16 -> deterministic 0.835 = harness
// reading bf16-pairs as fp32; rounds 1/5 read inputs as bf16 -> inf asq -> NaN).
// logits s[n,m] = (2*sum_c mk[c,n]*qk[c,m] - sum_c mk[c,n]^2)/8 ; softmax over n;
// out[c,m] = sum_n mv[c,n]*P[n,m].
// MFMA bf16 for both GEMMs; asq/exp/denom/out in fp32. No max-subtraction: logits
// bounded ~[-35,+15] for N(0,1) inputs -> fp32 exp cannot overflow.
// k_denom and k_main compute bit-identical exp weights -> exactly normalized softmax.

typedef unsigned short ushort_t;
typedef unsigned int uint_t;
typedef __attribute__((ext_vector_type(8))) short short8;
typedef __attribute__((ext_vector_type(4))) float floatx4;

#define MFMA16(a, b, c) __builtin_amdgcn_mfma_f32_16x16x32_bf16((a), (b), (c), 0, 0, 0)

__device__ __forceinline__ ushort_t f2b(float f) {
    uint_t b = __float_as_uint(f);
    b += 0x7FFFu + ((b >> 16) & 1u);   // RNE to bf16
    return (ushort_t)(b >> 16);
}

// Problem constants
#define BB 4
#define CK 64
#define NN 8192   // T*H*W
#define MM 1024   // H*W
#define CV 512

// ---- module-scope scratch (allocated at load; fully rewritten every call) ----
__device__ __align__(16) ushort_t g_mkT[BB * NN * CK];   // 4 MiB  bf16 mk^T [b][n][c]
__device__ __align__(16) float    g_asq8[BB * NN];       // 128 KiB fp32 (sum mk^2)/8
__device__ __align__(16) float    g_denom[BB * MM];      // 16 KiB fp32 softmax denoms
__device__ __align__(16) ushort_t g_mvb[BB * CV * NN];   // 32 MiB bf16 mv [b][c][n]

// ---------------------------------------------------------------------------
// K0: g_mkT[b][n][c] = bf16(mk[b][c][n]), g_asq8[b][n] = (sum_c mk^2)/8 (fp32).
// Also zeroes g_denom (stream-ordered before k_denom's atomics).
// ---------------------------------------------------------------------------
__global__ __launch_bounds__(256) void k_prep(const float* __restrict__ mk) {
    if (blockIdx.x < 16) g_denom[blockIdx.x * 256 + threadIdx.x] = 0.f;

    int t = blockIdx.x * 256 + threadIdx.x;   // 0 .. B*N-1
    int b = t >> 13;
    int n = t & (NN - 1);
    const float* src = mk + (size_t)b * CK * NN + n;
    ushort_t* dst = g_mkT + (size_t)t * CK;
    float acc = 0.f;
#pragma unroll
    for (int g = 0; g < 8; g++) {
        float f[8];
#pragma unroll
        for (int i = 0; i < 8; i++) {
            f[i] = src[(size_t)(g * 8 + i) * NN];
            acc += f[i] * f[i];
        }
        uint4 q;
        q.x = (uint_t)f2b(f[0]) | ((uint_t)f2b(f[1]) << 16);
        q.y = (uint_t)f2b(f[2]) | ((uint_t)f2b(f[3]) << 16);
        q.z = (uint_t)f2b(f[4]) | ((uint_t)f2b(f[5]) << 16);
        q.w = (uint_t)f2b(f[6]) | ((uint_t)f2b(f[7]) << 16);
        *(uint4*)(dst + g * 8) = q;
    }
    g_asq8[t] = acc * 0.125f;
}

// ---------------------------------------------------------------------------
// K0b: g_mvb = bf16(mv), flat. 8 elements/thread, fully coalesced.
// ---------------------------------------------------------------------------
__global__ __launch_bounds__(256) void k_mvconv(const float* __restrict__ mv) {
    size_t t = (size_t)blockIdx.x * 256 + threadIdx.x;
    const float4* s = (const float4*)mv + t * 2;
    float4 x = s[0], y = s[1];
    uint4 q;
    q.x = (uint_t)f2b(x.x) | ((uint_t)f2b(x.y) << 16);
    q.y = (uint_t)f2b(x.z) | ((uint_t)f2b(x.w) << 16);
    q.z = (uint_t)f2b(y.x) | ((uint_t)f2b(y.y) << 16);
    q.w = (uint_t)f2b(y.z) | ((uint_t)f2b(y.w) << 16);
    ((uint4*)g_mvb)[t] = q;
}

// ---------------------------------------------------------------------------
// K1: denom[b][m] = sum_n exp(s[n,m]).
// grid: b(4) x mtile(16, 64 q) x nsplit(8, 1024 n) = 512 blocks, 4 waves each.
// Layouts (m89/m91): A[m=lane&15][k=quad*8+j], B[n=lane&15][k=quad*8+j],
// D: col=lane&15 (B's row n), row=quad*4+reg (A's row m).
// ---------------------------------------------------------------------------
__global__ __launch_bounds__(256) void k_denom(const float* __restrict__ qk) {
    int bx = blockIdx.x;
    int b = bx >> 7;
    int rem = bx & 127;
    int mt = rem >> 3;
    int ns = rem & 7;
    int m0 = mt * 64;
    int nstart = ns * 1024;

    int tid = threadIdx.x;
    int w = tid >> 6;
    int lane = tid & 63;
    int quad = lane >> 4;
    int l15 = lane & 15;

    int mrow = m0 + w * 16 + l15;
    short8 aq0, aq1;
#pragma unroll
    for (int j = 0; j < 8; j++) {
        aq0[j] = (short)f2b(qk[(size_t)(b * CK + quad * 8 + j) * MM + mrow]);
        aq1[j] = (short)f2b(qk[(size_t)(b * CK + 32 + quad * 8 + j) * MM + mrow]);
    }

    float part0 = 0.f, part1 = 0.f, part2 = 0.f, part3 = 0.f;
    for (int n0 = nstart; n0 < nstart + 1024; n0 += 64) {
#pragma unroll
        for (int nt = 0; nt < 4; nt++) {
            int n_l = n0 + nt * 16 + l15;
            const ushort_t* kr = g_mkT + (size_t)(b * NN + n_l) * CK + quad * 8;
            short8 kb0 = *(const short8*)kr;
            short8 kb1 = *(const short8*)(kr + 32);
            floatx4 d = {0.f, 0.f, 0.f, 0.f};
            d = MFMA16(aq0, kb0, d);
            d = MFMA16(aq1, kb1, d);
            float sa = g_asq8[b * NN + n_l];
            part0 += __expf(d[0] * 0.25f - sa);
            part1 += __expf(d[1] * 0.25f - sa);
            part2 += __expf(d[2] * 0.25f - sa);
            part3 += __expf(d[3] * 0.25f - sa);
        }
    }
    // reduce across the 16 lanes (n) within each quad (xor bits 0..3 keep quad)
#pragma unroll
    for (int off = 1; off < 16; off <<= 1) {
        part0 += __shfl_xor(part0, off, 64);
        part1 += __shfl_xor(part1, off, 64);
        part2 += __shfl_xor(part2, off, 64);
        part3 += __shfl_xor(part3, off, 64);
    }
    if (l15 == 0) {
        float* dp = g_denom + b * MM + m0 + w * 16 + quad * 4;
        atomicAdd(dp + 0, part0);
        atomicAdd(dp + 1, part1);
        atomicAdd(dp + 2, part2);
        atomicAdd(dp + 3, part3);
    }
}

// ---------------------------------------------------------------------------
// K2: fused readout. grid 256: bx = mt16*16 + (b*4+cs) so all 16 blocks of one
// (b, c-slice) share bx mod 8 -> same XCD (L2 locality for the 2 MiB mv slice).
// block = 4 waves. Per 64-token n-step:
//   GEMM1: wave w computes P[w*16..+15][n0..+63] -> exp -> bf16 -> LDS
//   GEMM2: wave w accumulates acc[c slice w*32..+31][all 64 m]
// LDS P: [64 m][pitch 72] bf16 (row stride 144 B -> b128 reads 2-way alias = free).
// ---------------------------------------------------------------------------
__global__ __launch_bounds__(256) void k_main(const float* __restrict__ qk,
                                              float* __restrict__ out) {
    __shared__ __align__(16) ushort_t lds_p[64 * 72];

    int bx = blockIdx.x;
    int mt16 = bx >> 4;        // 0..15 -> m0
    int b = (bx >> 2) & 3;     // 0..3
    int cs = bx & 3;           // 0..3 -> c0
    int c0 = cs * 128;
    int m0 = mt16 * 64;

    int tid = threadIdx.x;
    int w = tid >> 6;
    int lane = tid & 63;
    int quad = lane >> 4;
    int l15 = lane & 15;

    // Q fragments for this wave's 16 m-rows, K=64 (2 chunks), held all loop.
    int mrow = m0 + w * 16 + l15;
    short8 aq0, aq1;
#pragma unroll
    for (int j = 0; j < 8; j++) {
        aq0[j] = (short)f2b(qk[(size_t)(b * CK + quad * 8 + j) * MM + mrow]);
        aq1[j] = (short)f2b(qk[(size_t)(b * CK + 32 + quad * 8 + j) * MM + mrow]);
    }

    floatx4 acc[2][4];
#pragma unroll
    for (int i = 0; i < 2; i++)
#pragma unroll
        for (int j = 0; j < 4; j++)
            acc[i][j] = (floatx4){0.f, 0.f, 0.f, 0.f};

    int mbase = w * 16 + quad * 4;

    for (int n0 = 0; n0 < NN; n0 += 64) {
        // ---- GEMM1: scores -> P in LDS ----
#pragma unroll
        for (int nt = 0; nt < 4; nt++) {
            int n_l = n0 + nt * 16 + l15;
            const ushort_t* kr = g_mkT + (size_t)(b * NN + n_l) * CK + quad * 8;
            short8 kb0 = *(const short8*)kr;
            short8 kb1 = *(const short8*)(kr + 32);
            floatx4 d = {0.f, 0.f, 0.f, 0.f};
            d = MFMA16(aq0, kb0, d);
            d = MFMA16(aq1, kb1, d);
            float sa = g_asq8[b * NN + n_l];
#pragma unroll
            for (int r = 0; r < 4; r++) {
                float p = __expf(d[r] * 0.25f - sa);
                lds_p[(mbase + r) * 72 + nt * 16 + l15] = f2b(p);
            }
        }
        __syncthreads();

        // ---- GEMM2: acc += V @ P^T  (A rows = c, B rows = m, k = n) ----
#pragma unroll
        for (int kc = 0; kc < 2; kc++) {
            short8 pb[4];
#pragma unroll
            for (int mt = 0; mt < 4; mt++)
                pb[mt] = *(const short8*)&lds_p[(mt * 16 + l15) * 72 + kc * 32 + quad * 8];
#pragma unroll
            for (int ctl = 0; ctl < 2; ctl++) {
                size_t vidx = (size_t)(b * CV + c0 + w * 32 + ctl * 16 + l15) * NN
                              + n0 + kc * 32 + quad * 8;
                short8 va = *(const short8*)(g_mvb + vidx);
#pragma unroll
                for (int mt = 0; mt < 4; mt++)
                    acc[ctl][mt] = MFMA16(va, pb[mt], acc[ctl][mt]);
            }
        }
        __syncthreads();
    }

    // ---- epilogue: normalize and store fp32 ----
#pragma unroll
    for (int mt = 0; mt < 4; mt++) {
        float rd = 1.0f / g_denom[b * MM + m0 + mt * 16 + l15];
#pragma unroll
        for (int ctl = 0; ctl < 2; ctl++) {
            int cbase = c0 + w * 32 + ctl * 16 + quad * 4;
            size_t obase = (size_t)(b * CV + cbase) * MM + m0 + mt * 16 + l15;
            out[obase + 0 * MM] = acc[ctl][mt][0] * rd;
            out[obase + 1 * MM] = acc[ctl][mt][1] * rd;
            out[obase + 2 * MM] = acc[ctl][mt][2] * rd;
            out[obase + 3 * MM] = acc[ctl][mt][3] * rd;
        }
    }
}

// ---------------------------------------------------------------------------
// launch — inputs identified BY SIZE (robust to any ordering convention).
// ---------------------------------------------------------------------------
extern "C" void kernel_launch(void* const* d_in, const int* in_sizes, int n_in,
                              void* d_out, int out_size, void* d_ws, size_t ws_size,
                              hipStream_t stream) {
    const float* mk = nullptr;   // 4*64*8192   = 2,097,152
    const float* qk = nullptr;   // 4*64*1024   =   262,144
    const float* mv = nullptr;   // 4*512*8192  = 16,777,216
    for (int i = 0; i < n_in; i++) {
        if (in_sizes[i] == BB * CK * NN)      mk = (const float*)d_in[i];
        else if (in_sizes[i] == BB * CK * MM) qk = (const float*)d_in[i];
        else if (in_sizes[i] == BB * CV * NN) mv = (const float*)d_in[i];
    }
    float* out = (float*)d_out;              // [4,512,32,32] fp32
    (void)d_ws; (void)ws_size; (void)out_size;

    const size_t mv_elems = (size_t)BB * CV * NN;   // 16,777,216

    k_prep<<<(BB * NN) / 256, 256, 0, stream>>>(mk);            // also zeroes g_denom
    k_mvconv<<<(int)(mv_elems / (8 * 256)), 256, 0, stream>>>(mv);
    k_denom<<<BB * 16 * 8, 256, 0, stream>>>(qk);
    k_main<<<BB * 4 * 16, 256, 0, stream>>>(qk, out);
}